// Round 9
// baseline (210.486 us; speedup 1.0000x reference)
//
#include <hip/hip_runtime.h>
#include <hip/hip_bf16.h>

// MultiHeadAttentionBlock: B=4, S=2048, D=512, H=8, DK=64, causal.
// R19: attn q-coarsening - 2-wave blocks, 32 q-rows per wave (two 16-row
//   groups A/B). Evidence (R10/R11/R12/R18): wall = ~1790 cyc per 16qx64kv
//   wave-iteration, invariant to blocks/CU, barriers, addressing, setprio;
//   no pipe saturated. Mechanism here: every kf/vf ds_read_b128 now feeds
//   BOTH q-groups (LDS reads per q halve: 20 b128/iter for 32q vs 36), and
//   the two groups' QK/softmax/PV chains are independent WITHIN the wave ->
//   2x ILP fills dep-chain bubbles (R11 shared across waves without ILP and
//   only for ~35% of computes; this is 100% + in-wave).
//   Same LDS layout/swizzles/staging; grid (32,32) class-balanced -> per-CU
//   66 iterations; 4 blocks/CU (40KB LDS), 8 waves/CU, 128-thr blocks.
//   qkv (A fp32 via gload_lds, cvt at LDS-read), oproj 64x64 4-wave,
//   cvt weights-only: unchanged from R16 (193.96us best).

#define BATCH  4
#define SLEN   2048
#define DMODEL 512
#define NHEAD  8
#define DHEAD  64
#define MROWS  (BATCH * SLEN)   // 8192

#define NQ ((size_t)MROWS * DMODEL)     // 4194304
#define NW ((size_t)DMODEL * DMODEL)    // 262144
#define NB ((size_t)DMODEL)             // 512
#define CVTW_TOTAL (4 * NW + 4 * NB)    // 1050624

#define SCALE_L2E 0.180336880f          // (1/8) * log2(e)

typedef short bf16x8 __attribute__((ext_vector_type(8)));
typedef float f32x4  __attribute__((ext_vector_type(4)));

typedef unsigned int __attribute__((address_space(1))) glb_u32_t;
typedef unsigned int __attribute__((address_space(3))) lds_u32_t;

__device__ __forceinline__ void async16(const void* g, void* l) {
    // 16B per lane, HW writes LDS at wave-uniform base + lane*16
    __builtin_amdgcn_global_load_lds((glb_u32_t*)g, (lds_u32_t*)l, 16, 0, 0);
}

__device__ __forceinline__ float bf2f(unsigned short u) {
    union { unsigned int i; float f; } v; v.i = ((unsigned int)u) << 16; return v.f;
}
__device__ __forceinline__ unsigned short f2bf(float f) {
    union { float f; unsigned int i; } v; v.f = f;
    unsigned int x = v.i;
    return (unsigned short)((x + 0x7fffu + ((x >> 16) & 1u)) >> 16);
}
__device__ __forceinline__ unsigned int pkbf(float a, float b) {
    union { __hip_bfloat162 h; unsigned int u; } cv;
    cv.h = __float22bfloat162_rn(float2{a, b});
    return cv.u;
}

__device__ __forceinline__ void wait0_barrier() {
    asm volatile("s_waitcnt vmcnt(0)" ::: "memory");
    __builtin_amdgcn_s_barrier();
    asm volatile("" ::: "memory");
}

// ---------------- cvt: WEIGHTS + BIASES only (4.2MB) ----------------
__global__ __launch_bounds__(256)
void cvt_w_kernel(const float* __restrict__ wq, const float* __restrict__ wk,
                  const float* __restrict__ wv, const float* __restrict__ wo,
                  const float* __restrict__ bq, const float* __restrict__ bk,
                  const float* __restrict__ bv, const float* __restrict__ bo,
                  unsigned short* __restrict__ dst)   // dst = wqb base
{
    const size_t i4 = ((size_t)blockIdx.x * 256 + threadIdx.x) * 4;
    if (i4 >= CVTW_TOTAL) return;
    const float* src;
    size_t off;
    if      (i4 <     NW)          { src = wq; off = i4; }
    else if (i4 < 2 * NW)          { src = wk; off = i4 - NW; }
    else if (i4 < 3 * NW)          { src = wv; off = i4 - 2 * NW; }
    else if (i4 < 4 * NW)          { src = wo; off = i4 - 3 * NW; }
    else if (i4 < 4 * NW + NB)     { src = bq; off = i4 - 4 * NW; }
    else if (i4 < 4 * NW + 2 * NB) { src = bk; off = i4 - 4 * NW - NB; }
    else if (i4 < 4 * NW + 3 * NB) { src = bv; off = i4 - 4 * NW - 2 * NB; }
    else                           { src = bo; off = i4 - 4 * NW - 3 * NB; }
    const float4 f = *(const float4*)(src + off);
    ushort4 o;
    o.x = f2bf(f.x); o.y = f2bf(f.y); o.z = f2bf(f.z); o.w = f2bf(f.w);
    *(ushort4*)(dst + i4) = o;
}

// ---------------- qkv GEMM body: C[M,512] = A_fp32 * W_bf16^T + b ----------------
// 128x128 tile, BK=32, 4 waves -> 64x64 each. A staged fp32 via gload_lds
// (dbuf 32KB, rows of 8 16B-chunks, phys = logical ^ (row&7)); converted to
// bf16 at LDS-read. W bf16 via gload_lds (rows of 4 chunks, phys = logical ^
// (row&3)). One barrier per K-iter. mode: 0=Q(scaled) 1=K 2=V^T store.
__device__ __forceinline__ void qkv_body(const float* __restrict__ A,
                                         const unsigned short* __restrict__ W,
                                         const unsigned short* __restrict__ bias,
                                         unsigned short* __restrict__ C,
                                         int mode, int m0, int n0,
                                         unsigned char* smem)
{
    float*          Asf = (float*)smem;                          // [2][128*32] f32 32KB
    unsigned short* Bs  = (unsigned short*)(smem + 32768);       // [2][128*32] bf16 16KB

    const int tid  = threadIdx.x;
    const int wave = tid >> 6;
    const int lane = tid & 63;
    const int l15  = lane & 15;
    const int quad = lane >> 4;
    const int wm   = (wave & 1) * 64;
    const int wn   = (wave >> 1) * 64;
    const int srow = lane >> 2;                         // W staging: 0..15
    const int scol = (((lane & 3) ^ (srow & 3)) * 8);   // W swizzled col (bf16)
    const int rswb = (quad ^ (l15 & 3)) * 8;            // W read swizzle
    const int krow = lane >> 3;                         // A staging: 0..7
    const int acol = ((lane & 7) ^ (krow & 7)) * 4;     // A swizzled col (f32)

    auto stageA = [&](int k0, int buf) {
        #pragma unroll
        for (int c = 0; c < 4; c++) {
            const int rb = c * 32 + wave * 8;
            async16(A + (size_t)(m0 + rb + krow) * DMODEL + k0 + acol,
                    Asf + (size_t)buf * 4096 + rb * 32);
        }
    };
    auto stageW = [&](int k0, int buf) {
        async16(W + (size_t)(n0 + wave * 16 + srow) * DMODEL + k0 + scol,
                Bs + (size_t)buf * 4096 + wave * 512);
        async16(W + (size_t)(n0 + (wave + 4) * 16 + srow) * DMODEL + k0 + scol,
                Bs + (size_t)buf * 4096 + (wave + 4) * 512);
    };

    f32x4 acc[4][4] = {};
    stageA(0, 0);
    stageW(0, 0);

    #pragma unroll 1
    for (int kt = 0; kt < 16; kt++) {
        const int cur = kt & 1;
        wait0_barrier();
        if (kt < 15) { stageA((kt + 1) * 32, cur ^ 1); stageW((kt + 1) * 32, cur ^ 1); }

        bf16x8 af[4], bfr[4];
        #pragma unroll
        for (int i = 0; i < 4; i++) {
            const int row = wm + i * 16 + l15;
            const float* rp = Asf + (size_t)cur * 4096 + row * 32;
            const f32x4 x = *(const f32x4*)(rp + (((quad * 2)     ^ (row & 7)) * 4));
            const f32x4 y = *(const f32x4*)(rp + (((quad * 2 + 1) ^ (row & 7)) * 4));
            union { bf16x8 v; unsigned int u[4]; } r;
            r.u[0] = pkbf(x[0], x[1]); r.u[1] = pkbf(x[2], x[3]);
            r.u[2] = pkbf(y[0], y[1]); r.u[3] = pkbf(y[2], y[3]);
            af[i] = r.v;
        }
        #pragma unroll
        for (int j = 0; j < 4; j++)
            bfr[j] = *(const bf16x8*)(Bs + (size_t)cur * 4096 + (wn + j * 16 + l15) * 32 + rswb);
        #pragma unroll
        for (int i = 0; i < 4; i++)
            #pragma unroll
            for (int j = 0; j < 4; j++)
                acc[i][j] = __builtin_amdgcn_mfma_f32_16x16x32_bf16(af[i], bfr[j], acc[i][j], 0, 0, 0);
    }

    // epilogue: C/D layout col = lane&15, row = quad*4 + reg
    if (mode == 2) {
        // V^T store: col -> (h,dk), row -> (b,s)
        #pragma unroll
        for (int j = 0; j < 4; j++) {
            const int col = n0 + wn + j * 16 + l15;
            const float bv = bf2f(bias[col]);
            const int hh = col >> 6, dk = col & 63;
            #pragma unroll
            for (int i = 0; i < 4; i++) {
                const int row = m0 + wm + i * 16 + quad * 4;
                const int bb = row >> 11, s = row & 2047;
                uint2 o2;
                o2.x = pkbf(acc[i][j][0] + bv, acc[i][j][1] + bv);
                o2.y = pkbf(acc[i][j][2] + bv, acc[i][j][3] + bv);
                *(uint2*)(C + ((size_t)((bb * NHEAD + hh) * DHEAD + dk)) * SLEN + s) = o2;
            }
        }
    } else {
        const float oscale = (mode == 0) ? SCALE_L2E : 1.0f;
        #pragma unroll
        for (int j = 0; j < 4; j++) {
            const int col = n0 + wn + j * 16 + l15;
            const float bv = bf2f(bias[col]);
            #pragma unroll
            for (int i = 0; i < 4; i++) {
                const int row = m0 + wm + i * 16 + quad * 4;
                #pragma unroll
                for (int r = 0; r < 4; r++)
                    C[(size_t)(row + r) * DMODEL + col] = f2bf((acc[i][j][r] + bv) * oscale);
            }
        }
    }
}

__global__ __launch_bounds__(256, 3)
void qkv_gemm_kernel(const float* __restrict__ qin, const float* __restrict__ kin,
                     const float* __restrict__ vin,
                     const unsigned short* __restrict__ wq, const unsigned short* __restrict__ bq,
                     const unsigned short* __restrict__ wk, const unsigned short* __restrict__ bk,
                     const unsigned short* __restrict__ wv, const unsigned short* __restrict__ bv,
                     unsigned short* __restrict__ qh, unsigned short* __restrict__ kh,
                     unsigned short* __restrict__ vt)
{
    __shared__ __align__(16) unsigned char smem[49152];
    const int z = blockIdx.z;
    const float*          A    = (z == 0) ? qin : (z == 1) ? kin : vin;
    const unsigned short* W    = (z == 0) ? wq  : (z == 1) ? wk  : wv;
    const unsigned short* bias = (z == 0) ? bq  : (z == 1) ? bk  : bv;
    unsigned short*       C    = (z == 0) ? qh  : (z == 1) ? kh  : vt;
    qkv_body(A, W, bias, C, z, blockIdx.x * 128, blockIdx.y * 128, smem);
}

// ---------------- Flash attention: 2 waves, 32 q-rows/wave (2x 16-row groups) ----
// Block: 64 q-rows of one (b,h); wave w owns rows w*32 + {0..15 (A), 16..31 (B)}.
// KV tiles of 64 staged via gload_lds into XOR-chunk-swizzled double buffers;
// one barrier/iter joins the 2 waves. Each kf/vf ds_read serves BOTH groups.
// Q pre-scaled by (1/8)log2e; fixed-reference softmax p = exp2(s).
// LDS: Ks 16K + Vs 16K + Ps 8K = 40960 B -> 4 blocks/CU (8 waves/CU).
__global__ __launch_bounds__(128, 2)
void attn_kernel(const unsigned short* __restrict__ qh,
                 const unsigned short* __restrict__ kh,
                 const unsigned short* __restrict__ vt,   // [B,H,DK,S]
                 unsigned short* __restrict__ ctx)
{
    __shared__ __align__(16) unsigned short Ks[2][64 * 64];   // [kv][dk], chunk-swizzled
    __shared__ __align__(16) unsigned short Vs[2][64 * 64];   // [dk][kv], chunk-swizzled
    __shared__ __align__(16) unsigned short Ps[2][2][16 * 64];// [wave][grp][q][kv]

    const int tid  = threadIdx.x;
    const int wave = tid >> 6;        // 0..1
    const int lane = tid & 63;
    const int l15  = lane & 15;
    const int quad = lane >> 4;

    const int bh = blockIdx.x;        // head-major: bh%8 -> XCD K/V L2 locality
    const int x  = blockIdx.y;        // 0..31
    const int g  = x & 7, s = x >> 3; // balanced classes: per-CU iters = 66
    const int qt = (s == 0) ? g : (s == 1) ? 15 - g : (s == 2) ? 16 + g : 31 - g;
    const int b  = bh >> 3;
    const int h  = bh & 7;

    const size_t base = (size_t)b * SLEN * DMODEL + (size_t)h * DHEAD;
    const unsigned short* Q  = qh + base;
    const unsigned short* K  = kh + base;
    const unsigned short* VT = vt + (size_t)bh * DHEAD * SLEN;

    // staging offsets (8 chunks of 16B per 128B row, chunk ^= row&7)
    const int krow_l = lane >> 3;                       // 0..7
    const int kcol_l = ((lane & 7) ^ (krow_l & 7)) * 8;

    const int qrowA = qt * 64 + wave * 32 + l15;        // group A
    const int qrowB = qrowA + 16;                       // group B
    const bf16x8 qa0 = *(const bf16x8*)(Q + (size_t)qrowA * DMODEL + quad * 8);
    const bf16x8 qa1 = *(const bf16x8*)(Q + (size_t)qrowA * DMODEL + 32 + quad * 8);
    const bf16x8 qb0 = *(const bf16x8*)(Q + (size_t)qrowB * DMODEL + quad * 8);
    const bf16x8 qb1 = *(const bf16x8*)(Q + (size_t)qrowB * DMODEL + 32 + quad * 8);

    // hoisted per-lane LDS offsets
    int kf_off[2][4];   // kf/vf reads share the formula (Ks vs Vs base differs)
    int pf_off[2];
    int pw_off[4];
    #pragma unroll
    for (int kk = 0; kk < 2; kk++) {
        pf_off[kk] = l15 * 64 + (((kk * 4 + quad) ^ (l15 & 7)) * 8);
        #pragma unroll
        for (int j = 0; j < 4; j++)
            kf_off[kk][j] = (j * 16 + l15) * 64 + (((kk * 4 + quad) ^ (l15 & 7)) * 8);
    }
    #pragma unroll
    for (int j = 0; j < 4; j++)
        pw_off[j] = l15 * 64 + (((j * 2 + (quad >> 1)) ^ (l15 & 7)) * 8) + (quad & 1) * 4;

    f32x4 oaccA[4] = {}, oaccB[4] = {};
    float lsumA = 0.0f, lsumB = 0.0f;
    unsigned short* PwA = &Ps[wave][0][0];
    unsigned short* PwB = &Ps[wave][1][0];
    const int ktiles = qt + 1;

    // each wave stages 32 K-rows and 32 V^T-rows (4 chunks of 8 rows each)
    auto stageKV = [&](int kt, int buf) {
        #pragma unroll
        for (int c = 0; c < 4; c++) {
            const int rb = wave * 32 + c * 8;
            async16(K + (size_t)(kt * 64 + rb + krow_l) * DMODEL + kcol_l,
                    &Ks[buf][0] + (wave * 4 + c) * 512);
            async16(VT + (size_t)(rb + krow_l) * SLEN + kt * 64 + kcol_l,
                    &Vs[buf][0] + (wave * 4 + c) * 512);
        }
    };

    auto packP = [&](f32x4* sacc, unsigned short* Pw, float& lsum) {
        #pragma unroll
        for (int j = 0; j < 4; j++) {
            const float p0 = exp2f(sacc[j][0]);
            const float p1 = exp2f(sacc[j][1]);
            const float p2v = exp2f(sacc[j][2]);
            const float p3 = exp2f(sacc[j][3]);
            lsum += (p0 + p1) + (p2v + p3);
            uint2 pw;
            pw.x = pkbf(p0, p1);
            pw.y = pkbf(p2v, p3);
            *(uint2*)(Pw + pw_off[j]) = pw;
        }
    };

    stageKV(0, 0);

    #pragma unroll 1
    for (int kt = 0; kt < ktiles; kt++) {
        const int cur = kt & 1;
        wait0_barrier();
        if (kt + 1 < ktiles) stageKV(kt + 1, cur ^ 1);

        // S^T = K Q^T for both q-groups; kf shared
        f32x4 sa[4] = {}, sb[4] = {};
        __builtin_amdgcn_s_setprio(1);
        #pragma unroll
        for (int kk = 0; kk < 2; kk++) {
            const bf16x8 qA = kk ? qa1 : qa0;
            const bf16x8 qB = kk ? qb1 : qb0;
            #pragma unroll
            for (int j = 0; j < 4; j++) {
                bf16x8 kf = *(const bf16x8*)(&Ks[cur][0] + kf_off[kk][j]);
                sa[j] = __builtin_amdgcn_mfma_f32_16x16x32_bf16(kf, qA, sa[j], 0, 0, 0);
                sb[j] = __builtin_amdgcn_mfma_f32_16x16x32_bf16(kf, qB, sb[j], 0, 0, 0);
            }
        }
        __builtin_amdgcn_s_setprio(0);

        if (kt == qt) {   // causal mask: diagonal tile only (both groups in-tile)
            #pragma unroll
            for (int j = 0; j < 4; j++)
                #pragma unroll
                for (int r = 0; r < 4; r++) {
                    const int kv = kt * 64 + j * 16 + quad * 4 + r;
                    if (kv > qrowA) sa[j][r] = -1e30f;
                    if (kv > qrowB) sb[j][r] = -1e30f;
                }
        }

        packP(sa, PwA, lsumA);
        packP(sb, PwB, lsumB);
        asm volatile("s_waitcnt lgkmcnt(0)" ::: "memory");   // same-wave P round-trip

        // O^T += V^T P^T for both groups; vf shared
        __builtin_amdgcn_s_setprio(1);
        #pragma unroll
        for (int kk = 0; kk < 2; kk++) {
            bf16x8 pfA = *(const bf16x8*)(PwA + pf_off[kk]);
            bf16x8 pfB = *(const bf16x8*)(PwB + pf_off[kk]);
            #pragma unroll
            for (int jd = 0; jd < 4; jd++) {
                bf16x8 vf = *(const bf16x8*)(&Vs[cur][0] + kf_off[kk][jd]);
                oaccA[jd] = __builtin_amdgcn_mfma_f32_16x16x32_bf16(vf, pfA, oaccA[jd], 0, 0, 0);
                oaccB[jd] = __builtin_amdgcn_mfma_f32_16x16x32_bf16(vf, pfB, oaccB[jd], 0, 0, 0);
            }
        }
        __builtin_amdgcn_s_setprio(0);
    }

    // l reductions across the 4 quads sharing each q row, then store both groups
    {
        float la = lsumA;
        la += __shfl_xor(la, 16, 64);
        la += __shfl_xor(la, 32, 64);
        const float invl = 1.0f / la;
        #pragma unroll
        for (int jd = 0; jd < 4; jd++) {
            uint2 o2;
            o2.x = pkbf(oaccA[jd][0] * invl, oaccA[jd][1] * invl);
            o2.y = pkbf(oaccA[jd][2] * invl, oaccA[jd][3] * invl);
            *(uint2*)(ctx + base + (size_t)qrowA * DMODEL + jd * 16 + quad * 4) = o2;
        }
    }
    {
        float lb = lsumB;
        lb += __shfl_xor(lb, 16, 64);
        lb += __shfl_xor(lb, 32, 64);
        const float invl = 1.0f / lb;
        #pragma unroll
        for (int jd = 0; jd < 4; jd++) {
            uint2 o2;
            o2.x = pkbf(oaccB[jd][0] * invl, oaccB[jd][1] * invl);
            o2.y = pkbf(oaccB[jd][2] * invl, oaccB[jd][3] * invl);
            *(uint2*)(ctx + base + (size_t)qrowB * DMODEL + jd * 16 + quad * 4) = o2;
        }
    }
}

// ---------------- oproj body: out[M,512] = ctx_bf16 * Wo^T + bo ----------------
// 64x64 tile, 4 waves -> 32x32 each. LDS 16KB dbuf, gload_lds, XOR swizzle.
// 1024 blocks = 4/CU.
__device__ __forceinline__ void oproj_body(const unsigned short* __restrict__ ctx,
                                           const unsigned short* __restrict__ wo,
                                           const unsigned short* __restrict__ bo,
                                           float* __restrict__ out,
                                           int m0, int n0, unsigned char* smem)
{
    unsigned short* As = (unsigned short*)smem;   // [2][64*32]
    unsigned short* Bs = As + 2 * 64 * 32;        // [2][64*32]

    const int tid  = threadIdx.x;
    const int wave = tid >> 6;
    const int lane = tid & 63;
    const int l15  = lane & 15;
    const int quad = lane >> 4;
    const int wm   = (wave & 1) * 32;
    const int wn   = (wave >> 1) * 32;
    const int srow = lane >> 2;
    const int scol = (((lane & 3) ^ (srow & 3)) * 8);
    const int rsw  = (quad ^ (l15 & 3)) * 8;

    auto stage = [&](int k0, int buf) {
        async16(ctx + (size_t)(m0 + wave * 16 + srow) * DMODEL + k0 + scol,
                As + (size_t)buf * 2048 + wave * 512);
        async16(wo + (size_t)(n0 + wave * 16 + srow) * DMODEL + k0 + scol,
                Bs + (size_t)buf * 2048 + wave * 512);
    };

    f32x4 acc[2][2] = {};
    stage(0, 0);

    #pragma unroll 1
    for (int kt = 0; kt < 16; kt++) {
        const int cur = kt & 1;
        wait0_barrier();
        if (kt < 15) stage((kt + 1) * 32, cur ^ 1);

        bf16x8 af[2], bfr[2];
        #pragma unroll
        for (int i = 0; i < 2; i++)
            af[i] = *(const bf16x8*)(As + (size_t)cur * 2048 + (wm + i * 16 + l15) * 32 + rsw);
        #pragma unroll
        for (int j = 0; j < 2; j++)
            bfr[j] = *(const bf16x8*)(Bs + (size_t)cur * 2048 + (wn + j * 16 + l15) * 32 + rsw);
        #pragma unroll
        for (int i = 0; i < 2; i++)
            #pragma unroll
            for (int j = 0; j < 2; j++)
                acc[i][j] = __builtin_amdgcn_mfma_f32_16x16x32_bf16(af[i], bfr[j], acc[i][j], 0, 0, 0);
    }

    #pragma unroll
    for (int j = 0; j < 2; j++) {
        const int col = n0 + wn + j * 16 + l15;
        const float bv = bf2f(bo[col]);
        #pragma unroll
        for (int i = 0; i < 2; i++) {
            const int row = m0 + wm + i * 16 + quad * 4;
            #pragma unroll
            for (int r = 0; r < 4; r++)
                out[(size_t)(row + r) * DMODEL + col] = acc[i][j][r] + bv;
        }
    }
}

__global__ __launch_bounds__(256, 4)
void oproj_gemm_kernel(const unsigned short* __restrict__ ctx,
                       const unsigned short* __restrict__ wo,
                       const unsigned short* __restrict__ bo,
                       float* __restrict__ out)
{
    __shared__ __align__(16) unsigned char smem[16384];
    oproj_body(ctx, wo, bo, out, blockIdx.x * 64, blockIdx.y * 64, smem);
}

extern "C" void kernel_launch(void* const* d_in, const int* in_sizes, int n_in,
                              void* d_out, int out_size, void* d_ws, size_t ws_size,
                              hipStream_t stream)
{
    const float* q   = (const float*)d_in[0];
    const float* k   = (const float*)d_in[1];
    const float* v   = (const float*)d_in[2];
    // d_in[3] = causal mask (int32) — causality implemented directly
    const float* w_q = (const float*)d_in[4];
    const float* b_q = (const float*)d_in[5];
    const float* w_k = (const float*)d_in[6];
    const float* b_k = (const float*)d_in[7];
    const float* w_v = (const float*)d_in[8];
    const float* b_v = (const float*)d_in[9];
    const float* w_o = (const float*)d_in[10];
    const float* b_o = (const float*)d_in[11];
    float* out = (float*)d_out;
    unsigned short* ws = (unsigned short*)d_ws;

    // bf16 workspace layout (elements); activation slots unused (A read fp32).
    unsigned short* wqb = ws + 3 * NQ;              // NW
    unsigned short* wkb = wqb + NW;
    unsigned short* wvb = wkb + NW;
    unsigned short* wob = wvb + NW;
    unsigned short* bqb = wob + NW;                 // NB
    unsigned short* bkb = bqb + NB;
    unsigned short* bvb = bkb + NB;
    unsigned short* bob = bvb + NB;
    unsigned short* qh  = bob + NB;                 // NQ each below
    unsigned short* kh  = qh + NQ;
    unsigned short* vt  = kh + NQ;                  // [B,H,DK,S]
    unsigned short* ctx = vt + NQ;

    dim3 blk(256);
    hipLaunchKernelGGL(cvt_w_kernel, dim3((unsigned)(CVTW_TOTAL / 4 / 256)), blk, 0, stream,
                       w_q, w_k, w_v, w_o, b_q, b_k, b_v, b_o, wqb);
    hipLaunchKernelGGL(qkv_gemm_kernel, dim3(MROWS / 128, DMODEL / 128, 3), blk, 0, stream,
                       q, k, v, wqb, bqb, wkb, bkb, wvb, bvb, qh, kh, vt);
    hipLaunchKernelGGL(attn_kernel, dim3(BATCH * NHEAD, 32), dim3(128), 0, stream,
                       qh, kh, vt, ctx);
    hipLaunchKernelGGL(oproj_gemm_kernel, dim3(MROWS / 64, DMODEL / 64), blk, 0, stream,
                       ctx, wob, bob, out);
}

// Round 10
// 189.855 us; speedup vs baseline: 1.1087x; 1.1087x over previous
//
#include <hip/hip_runtime.h>
#include <hip/hip_bf16.h>

// MultiHeadAttentionBlock: B=4, S=2048, D=512, H=8, DK=64, causal.
// R20: XCD-cosched for qkv/oproj; attn reverted to R16/R18 best (48.7us).
//   R19 post-mortem: q-coarsening traded TLP for ILP and lost (61.7us,
//   occupancy 11%); five attn restructures all >= R16 -> attn is converged.
//   New target = HBM redundancy in the GEMMs:
//     qkv: each A-tile (256KB fp32) re-read by 4 n-blocks -> 192MB A traffic.
//     oproj: each ctx-tile re-read by 8 n-blocks -> 128MB ctx traffic.
//   Fix: 1D grids with id chosen so same-tile readers differ by multiples
//   of 8 -> same XCD (round-robin dispatch), co-resident (qkv 768 = 3/CU
//   exact; oproj 1024 = 4/CU exact) -> 1 HBM fetch + rest L2 hits.
//     qkv:  id = n*192 + z*64 + m  (XCD = m%8; 4 n-readers share (z,m) A-tile)
//     oproj: id = n*128 + m        (XCD = m%8; 8 n-readers share ctx m-tile)
//   Predicted: A 192->48MB, ctx 128->16MB, dur 194 -> ~170-180us.

#define BATCH  4
#define SLEN   2048
#define DMODEL 512
#define NHEAD  8
#define DHEAD  64
#define MROWS  (BATCH * SLEN)   // 8192

#define NQ ((size_t)MROWS * DMODEL)     // 4194304
#define NW ((size_t)DMODEL * DMODEL)    // 262144
#define NB ((size_t)DMODEL)             // 512
#define CVTW_TOTAL (4 * NW + 4 * NB)    // 1050624

#define SCALE_L2E 0.180336880f          // (1/8) * log2(e)

typedef short bf16x8 __attribute__((ext_vector_type(8)));
typedef float f32x4  __attribute__((ext_vector_type(4)));

typedef unsigned int __attribute__((address_space(1))) glb_u32_t;
typedef unsigned int __attribute__((address_space(3))) lds_u32_t;

__device__ __forceinline__ void async16(const void* g, void* l) {
    // 16B per lane, HW writes LDS at wave-uniform base + lane*16
    __builtin_amdgcn_global_load_lds((glb_u32_t*)g, (lds_u32_t*)l, 16, 0, 0);
}

__device__ __forceinline__ float bf2f(unsigned short u) {
    union { unsigned int i; float f; } v; v.i = ((unsigned int)u) << 16; return v.f;
}
__device__ __forceinline__ unsigned short f2bf(float f) {
    union { float f; unsigned int i; } v; v.f = f;
    unsigned int x = v.i;
    return (unsigned short)((x + 0x7fffu + ((x >> 16) & 1u)) >> 16);
}
__device__ __forceinline__ unsigned int pkbf(float a, float b) {
    union { __hip_bfloat162 h; unsigned int u; } cv;
    cv.h = __float22bfloat162_rn(float2{a, b});
    return cv.u;
}

__device__ __forceinline__ void wait0_barrier() {
    asm volatile("s_waitcnt vmcnt(0)" ::: "memory");
    __builtin_amdgcn_s_barrier();
    asm volatile("" ::: "memory");
}

// ---------------- cvt: WEIGHTS + BIASES only (4.2MB) ----------------
__global__ __launch_bounds__(256)
void cvt_w_kernel(const float* __restrict__ wq, const float* __restrict__ wk,
                  const float* __restrict__ wv, const float* __restrict__ wo,
                  const float* __restrict__ bq, const float* __restrict__ bk,
                  const float* __restrict__ bv, const float* __restrict__ bo,
                  unsigned short* __restrict__ dst)   // dst = wqb base
{
    const size_t i4 = ((size_t)blockIdx.x * 256 + threadIdx.x) * 4;
    if (i4 >= CVTW_TOTAL) return;
    const float* src;
    size_t off;
    if      (i4 <     NW)          { src = wq; off = i4; }
    else if (i4 < 2 * NW)          { src = wk; off = i4 - NW; }
    else if (i4 < 3 * NW)          { src = wv; off = i4 - 2 * NW; }
    else if (i4 < 4 * NW)          { src = wo; off = i4 - 3 * NW; }
    else if (i4 < 4 * NW + NB)     { src = bq; off = i4 - 4 * NW; }
    else if (i4 < 4 * NW + 2 * NB) { src = bk; off = i4 - 4 * NW - NB; }
    else if (i4 < 4 * NW + 3 * NB) { src = bv; off = i4 - 4 * NW - 2 * NB; }
    else                           { src = bo; off = i4 - 4 * NW - 3 * NB; }
    const float4 f = *(const float4*)(src + off);
    ushort4 o;
    o.x = f2bf(f.x); o.y = f2bf(f.y); o.z = f2bf(f.z); o.w = f2bf(f.w);
    *(ushort4*)(dst + i4) = o;
}

// ---------------- qkv GEMM body: C[M,512] = A_fp32 * W_bf16^T + b ----------------
// 128x128 tile, BK=32, 4 waves -> 64x64 each. A staged fp32 via gload_lds
// (dbuf 32KB, rows of 8 16B-chunks, phys = logical ^ (row&7)); converted to
// bf16 at LDS-read. W bf16 via gload_lds (rows of 4 chunks, phys = logical ^
// (row&3)). One barrier per K-iter. mode: 0=Q(scaled) 1=K 2=V^T store.
__device__ __forceinline__ void qkv_body(const float* __restrict__ A,
                                         const unsigned short* __restrict__ W,
                                         const unsigned short* __restrict__ bias,
                                         unsigned short* __restrict__ C,
                                         int mode, int m0, int n0,
                                         unsigned char* smem)
{
    float*          Asf = (float*)smem;                          // [2][128*32] f32 32KB
    unsigned short* Bs  = (unsigned short*)(smem + 32768);       // [2][128*32] bf16 16KB

    const int tid  = threadIdx.x;
    const int wave = tid >> 6;
    const int lane = tid & 63;
    const int l15  = lane & 15;
    const int quad = lane >> 4;
    const int wm   = (wave & 1) * 64;
    const int wn   = (wave >> 1) * 64;
    const int srow = lane >> 2;                         // W staging: 0..15
    const int scol = (((lane & 3) ^ (srow & 3)) * 8);   // W swizzled col (bf16)
    const int rswb = (quad ^ (l15 & 3)) * 8;            // W read swizzle
    const int krow = lane >> 3;                         // A staging: 0..7
    const int acol = ((lane & 7) ^ (krow & 7)) * 4;     // A swizzled col (f32)

    auto stageA = [&](int k0, int buf) {
        #pragma unroll
        for (int c = 0; c < 4; c++) {
            const int rb = c * 32 + wave * 8;
            async16(A + (size_t)(m0 + rb + krow) * DMODEL + k0 + acol,
                    Asf + (size_t)buf * 4096 + rb * 32);
        }
    };
    auto stageW = [&](int k0, int buf) {
        async16(W + (size_t)(n0 + wave * 16 + srow) * DMODEL + k0 + scol,
                Bs + (size_t)buf * 4096 + wave * 512);
        async16(W + (size_t)(n0 + (wave + 4) * 16 + srow) * DMODEL + k0 + scol,
                Bs + (size_t)buf * 4096 + (wave + 4) * 512);
    };

    f32x4 acc[4][4] = {};
    stageA(0, 0);
    stageW(0, 0);

    #pragma unroll 1
    for (int kt = 0; kt < 16; kt++) {
        const int cur = kt & 1;
        wait0_barrier();
        if (kt < 15) { stageA((kt + 1) * 32, cur ^ 1); stageW((kt + 1) * 32, cur ^ 1); }

        bf16x8 af[4], bfr[4];
        #pragma unroll
        for (int i = 0; i < 4; i++) {
            const int row = wm + i * 16 + l15;
            const float* rp = Asf + (size_t)cur * 4096 + row * 32;
            const f32x4 x = *(const f32x4*)(rp + (((quad * 2)     ^ (row & 7)) * 4));
            const f32x4 y = *(const f32x4*)(rp + (((quad * 2 + 1) ^ (row & 7)) * 4));
            union { bf16x8 v; unsigned int u[4]; } r;
            r.u[0] = pkbf(x[0], x[1]); r.u[1] = pkbf(x[2], x[3]);
            r.u[2] = pkbf(y[0], y[1]); r.u[3] = pkbf(y[2], y[3]);
            af[i] = r.v;
        }
        #pragma unroll
        for (int j = 0; j < 4; j++)
            bfr[j] = *(const bf16x8*)(Bs + (size_t)cur * 4096 + (wn + j * 16 + l15) * 32 + rswb);
        #pragma unroll
        for (int i = 0; i < 4; i++)
            #pragma unroll
            for (int j = 0; j < 4; j++)
                acc[i][j] = __builtin_amdgcn_mfma_f32_16x16x32_bf16(af[i], bfr[j], acc[i][j], 0, 0, 0);
    }

    // epilogue: C/D layout col = lane&15, row = quad*4 + reg
    if (mode == 2) {
        // V^T store: col -> (h,dk), row -> (b,s)
        #pragma unroll
        for (int j = 0; j < 4; j++) {
            const int col = n0 + wn + j * 16 + l15;
            const float bv = bf2f(bias[col]);
            const int hh = col >> 6, dk = col & 63;
            #pragma unroll
            for (int i = 0; i < 4; i++) {
                const int row = m0 + wm + i * 16 + quad * 4;
                const int bb = row >> 11, s = row & 2047;
                uint2 o2;
                o2.x = pkbf(acc[i][j][0] + bv, acc[i][j][1] + bv);
                o2.y = pkbf(acc[i][j][2] + bv, acc[i][j][3] + bv);
                *(uint2*)(C + ((size_t)((bb * NHEAD + hh) * DHEAD + dk)) * SLEN + s) = o2;
            }
        }
    } else {
        const float oscale = (mode == 0) ? SCALE_L2E : 1.0f;
        #pragma unroll
        for (int j = 0; j < 4; j++) {
            const int col = n0 + wn + j * 16 + l15;
            const float bv = bf2f(bias[col]);
            #pragma unroll
            for (int i = 0; i < 4; i++) {
                const int row = m0 + wm + i * 16 + quad * 4;
                #pragma unroll
                for (int r = 0; r < 4; r++)
                    C[(size_t)(row + r) * DMODEL + col] = f2bf((acc[i][j][r] + bv) * oscale);
            }
        }
    }
}

// R20: 1D grid 768 = 3 blocks/CU exact (all co-resident).
// id = n*192 + z*64 + m -> XCD = id%8 = m%8: the 4 n-readers of each (z,m)
// A-tile are co-resident on ONE XCD -> A fetched from HBM once, 3 L2 hits.
__global__ __launch_bounds__(256, 3)
void qkv_gemm_kernel(const float* __restrict__ qin, const float* __restrict__ kin,
                     const float* __restrict__ vin,
                     const unsigned short* __restrict__ wq, const unsigned short* __restrict__ bq,
                     const unsigned short* __restrict__ wk, const unsigned short* __restrict__ bk,
                     const unsigned short* __restrict__ wv, const unsigned short* __restrict__ bv,
                     unsigned short* __restrict__ qh, unsigned short* __restrict__ kh,
                     unsigned short* __restrict__ vt)
{
    __shared__ __align__(16) unsigned char smem[49152];
    const int id = blockIdx.x;        // 0..767
    const int n  = id / 192;          // 0..3
    const int r  = id - n * 192;
    const int z  = r >> 6;            // 0..2
    const int m  = r & 63;            // 0..63
    const float*          A    = (z == 0) ? qin : (z == 1) ? kin : vin;
    const unsigned short* W    = (z == 0) ? wq  : (z == 1) ? wk  : wv;
    const unsigned short* bias = (z == 0) ? bq  : (z == 1) ? bk  : bv;
    unsigned short*       C    = (z == 0) ? qh  : (z == 1) ? kh  : vt;
    qkv_body(A, W, bias, C, z, m * 128, n * 128, smem);
}

// ---------------- Flash attention (R16 structure, best measured 48.7us) ----------------
// One 64-row q-tile of one (b,h); 4 waves x 16 q. KV tiles of 64 staged via
// gload_lds into XOR-chunk-swizzled double buffers; one barrier/iter.
// Q pre-scaled by (1/8)log2e; fixed-reference softmax p = exp2(s).
// LDS: Ks 16K + Vs 16K + Ps 8K = 40960 B -> 4 blocks/CU.
__global__ __launch_bounds__(256, 4)
void attn_kernel(const unsigned short* __restrict__ qh,
                 const unsigned short* __restrict__ kh,
                 const unsigned short* __restrict__ vt,   // [B,H,DK,S]
                 unsigned short* __restrict__ ctx)
{
    __shared__ __align__(16) unsigned short Ks[2][64 * 64];   // [kv][dk], chunk-swizzled
    __shared__ __align__(16) unsigned short Vs[2][64 * 64];   // [dk][kv], chunk-swizzled
    __shared__ __align__(16) unsigned short Ps[4][16 * 64];   // per-wave [q][kv], chunk-swizzled

    const int tid  = threadIdx.x;
    const int wave = tid >> 6;
    const int lane = tid & 63;
    const int l15  = lane & 15;
    const int quad = lane >> 4;

    const int bh = blockIdx.x;        // head-major: bh%8 -> XCD K/V L2 locality
    const int x  = blockIdx.y;        // 0..31
    const int g  = x & 7, s = x >> 3; // balanced classes: per-CU iters = 66
    const int qt = (s == 0) ? g : (s == 1) ? 15 - g : (s == 2) ? 16 + g : 31 - g;
    const int b  = bh >> 3;
    const int h  = bh & 7;

    const size_t base = (size_t)b * SLEN * DMODEL + (size_t)h * DHEAD;
    const unsigned short* Q  = qh + base;
    const unsigned short* K  = kh + base;
    const unsigned short* VT = vt + (size_t)bh * DHEAD * SLEN;

    // staging offsets (8 chunks of 16B per 128B row, chunk ^= row&7)
    const int krow_l = lane >> 3;
    const int kcol_l = ((lane & 7) ^ (krow_l & 7)) * 8;

    const int qrow = qt * 64 + wave * 16 + l15;
    const bf16x8 qf0 = *(const bf16x8*)(Q + (size_t)qrow * DMODEL + quad * 8);
    const bf16x8 qf1 = *(const bf16x8*)(Q + (size_t)qrow * DMODEL + 32 + quad * 8);

    f32x4 oacc[4] = {};
    float lsum = 0.0f;
    unsigned short* Pw = &Ps[wave][0];
    const int ktiles = qt + 1;

    auto stageKV = [&](int kt, int buf) {
        async16(K + (size_t)(kt * 64 + wave * 8 + krow_l) * DMODEL + kcol_l,
                &Ks[buf][0] + wave * 512);
        async16(K + (size_t)(kt * 64 + (wave + 4) * 8 + krow_l) * DMODEL + kcol_l,
                &Ks[buf][0] + (wave + 4) * 512);
        async16(VT + (size_t)(wave * 8 + krow_l) * SLEN + kt * 64 + kcol_l,
                &Vs[buf][0] + wave * 512);
        async16(VT + (size_t)((wave + 4) * 8 + krow_l) * SLEN + kt * 64 + kcol_l,
                &Vs[buf][0] + (wave + 4) * 512);
    };

    stageKV(0, 0);

    #pragma unroll 1
    for (int kt = 0; kt < ktiles; kt++) {
        const int cur = kt & 1;
        wait0_barrier();
        if (kt + 1 < ktiles) stageKV(kt + 1, cur ^ 1);

        // S^T = K Q^T
        f32x4 sacc[4] = {};
        #pragma unroll
        for (int kk = 0; kk < 2; kk++) {
            const bf16x8 qf = kk ? qf1 : qf0;
            #pragma unroll
            for (int j = 0; j < 4; j++) {
                bf16x8 kf = *(const bf16x8*)(&Ks[cur][0] + (j * 16 + l15) * 64
                                                + (((kk * 4 + quad) ^ (l15 & 7)) * 8));
                sacc[j] = __builtin_amdgcn_mfma_f32_16x16x32_bf16(kf, qf, sacc[j], 0, 0, 0);
            }
        }

        if (kt == qt) {   // causal mask: diagonal tile only
            #pragma unroll
            for (int j = 0; j < 4; j++)
                #pragma unroll
                for (int r = 0; r < 4; r++) {
                    const int kv = kt * 64 + j * 16 + quad * 4 + r;
                    if (kv > qrow) sacc[j][r] = -1e30f;
                }
        }

        // p = exp2(s); accumulate l; pack P^T -> Ps[q][kv] (XOR chunk swizzle)
        #pragma unroll
        for (int j = 0; j < 4; j++) {
            const float p0 = exp2f(sacc[j][0]);
            const float p1 = exp2f(sacc[j][1]);
            const float p2v = exp2f(sacc[j][2]);
            const float p3 = exp2f(sacc[j][3]);
            lsum += (p0 + p1) + (p2v + p3);
            uint2 pw;
            pw.x = pkbf(p0, p1);
            pw.y = pkbf(p2v, p3);
            const int chunk = (j * 2 + (quad >> 1)) ^ (l15 & 7);
            *(uint2*)(Pw + l15 * 64 + chunk * 8 + (quad & 1) * 4) = pw;
        }
        asm volatile("s_waitcnt lgkmcnt(0)" ::: "memory");   // same-wave P round-trip

        // O^T += V^T P^T
        #pragma unroll
        for (int kk = 0; kk < 2; kk++) {
            bf16x8 pf = *(const bf16x8*)(Pw + l15 * 64 + (((kk * 4 + quad) ^ (l15 & 7)) * 8));
            #pragma unroll
            for (int jd = 0; jd < 4; jd++) {
                bf16x8 vf = *(const bf16x8*)(&Vs[cur][0] + (jd * 16 + l15) * 64
                                                + (((kk * 4 + quad) ^ (l15 & 7)) * 8));
                oacc[jd] = __builtin_amdgcn_mfma_f32_16x16x32_bf16(vf, pf, oacc[jd], 0, 0, 0);
            }
        }
    }

    lsum += __shfl_xor(lsum, 16, 64);
    lsum += __shfl_xor(lsum, 32, 64);
    const float invl = 1.0f / lsum;

    #pragma unroll
    for (int jd = 0; jd < 4; jd++) {
        uint2 o2;
        o2.x = pkbf(oacc[jd][0] * invl, oacc[jd][1] * invl);
        o2.y = pkbf(oacc[jd][2] * invl, oacc[jd][3] * invl);
        *(uint2*)(ctx + base + (size_t)qrow * DMODEL + jd * 16 + quad * 4) = o2;
    }
}

// ---------------- oproj body: out[M,512] = ctx_bf16 * Wo^T + bo ----------------
// 64x64 tile, 4 waves -> 32x32 each. LDS 16KB dbuf, gload_lds, XOR swizzle.
__device__ __forceinline__ void oproj_body(const unsigned short* __restrict__ ctx,
                                           const unsigned short* __restrict__ wo,
                                           const unsigned short* __restrict__ bo,
                                           float* __restrict__ out,
                                           int m0, int n0, unsigned char* smem)
{
    unsigned short* As = (unsigned short*)smem;   // [2][64*32]
    unsigned short* Bs = As + 2 * 64 * 32;        // [2][64*32]

    const int tid  = threadIdx.x;
    const int wave = tid >> 6;
    const int lane = tid & 63;
    const int l15  = lane & 15;
    const int quad = lane >> 4;
    const int wm   = (wave & 1) * 32;
    const int wn   = (wave >> 1) * 32;
    const int srow = lane >> 2;
    const int scol = (((lane & 3) ^ (srow & 3)) * 8);
    const int rsw  = (quad ^ (l15 & 3)) * 8;

    auto stage = [&](int k0, int buf) {
        async16(ctx + (size_t)(m0 + wave * 16 + srow) * DMODEL + k0 + scol,
                As + (size_t)buf * 2048 + wave * 512);
        async16(wo + (size_t)(n0 + wave * 16 + srow) * DMODEL + k0 + scol,
                Bs + (size_t)buf * 2048 + wave * 512);
    };

    f32x4 acc[2][2] = {};
    stage(0, 0);

    #pragma unroll 1
    for (int kt = 0; kt < 16; kt++) {
        const int cur = kt & 1;
        wait0_barrier();
        if (kt < 15) stage((kt + 1) * 32, cur ^ 1);

        bf16x8 af[2], bfr[2];
        #pragma unroll
        for (int i = 0; i < 2; i++)
            af[i] = *(const bf16x8*)(As + (size_t)cur * 2048 + (wm + i * 16 + l15) * 32 + rsw);
        #pragma unroll
        for (int j = 0; j < 2; j++)
            bfr[j] = *(const bf16x8*)(Bs + (size_t)cur * 2048 + (wn + j * 16 + l15) * 32 + rsw);
        #pragma unroll
        for (int i = 0; i < 2; i++)
            #pragma unroll
            for (int j = 0; j < 2; j++)
                acc[i][j] = __builtin_amdgcn_mfma_f32_16x16x32_bf16(af[i], bfr[j], acc[i][j], 0, 0, 0);
    }

    #pragma unroll
    for (int j = 0; j < 2; j++) {
        const int col = n0 + wn + j * 16 + l15;
        const float bv = bf2f(bo[col]);
        #pragma unroll
        for (int i = 0; i < 2; i++) {
            const int row = m0 + wm + i * 16 + quad * 4;
            #pragma unroll
            for (int r = 0; r < 4; r++)
                out[(size_t)(row + r) * DMODEL + col] = acc[i][j][r] + bv;
        }
    }
}

// R20: 1D grid 1024 = 4 blocks/CU exact. id = n*128 + m -> XCD = m%8:
// the 8 n-readers of each ctx m-tile share one XCD -> ctx fetched once.
__global__ __launch_bounds__(256, 4)
void oproj_gemm_kernel(const unsigned short* __restrict__ ctx,
                       const unsigned short* __restrict__ wo,
                       const unsigned short* __restrict__ bo,
                       float* __restrict__ out)
{
    __shared__ __align__(16) unsigned char smem[16384];
    const int id = blockIdx.x;        // 0..1023
    const int n  = id >> 7;           // 0..7
    const int m  = id & 127;          // 0..127
    oproj_body(ctx, wo, bo, out, m * 64, n * 64, smem);
}

extern "C" void kernel_launch(void* const* d_in, const int* in_sizes, int n_in,
                              void* d_out, int out_size, void* d_ws, size_t ws_size,
                              hipStream_t stream)
{
    const float* q   = (const float*)d_in[0];
    const float* k   = (const float*)d_in[1];
    const float* v   = (const float*)d_in[2];
    // d_in[3] = causal mask (int32) — causality implemented directly
    const float* w_q = (const float*)d_in[4];
    const float* b_q = (const float*)d_in[5];
    const float* w_k = (const float*)d_in[6];
    const float* b_k = (const float*)d_in[7];
    const float* w_v = (const float*)d_in[8];
    const float* b_v = (const float*)d_in[9];
    const float* w_o = (const float*)d_in[10];
    const float* b_o = (const float*)d_in[11];
    float* out = (float*)d_out;
    unsigned short* ws = (unsigned short*)d_ws;

    // bf16 workspace layout (elements); activation slots unused (A read fp32).
    unsigned short* wqb = ws + 3 * NQ;              // NW
    unsigned short* wkb = wqb + NW;
    unsigned short* wvb = wkb + NW;
    unsigned short* wob = wvb + NW;
    unsigned short* bqb = wob + NW;                 // NB
    unsigned short* bkb = bqb + NB;
    unsigned short* bvb = bkb + NB;
    unsigned short* bob = bvb + NB;
    unsigned short* qh  = bob + NB;                 // NQ each below
    unsigned short* kh  = qh + NQ;
    unsigned short* vt  = kh + NQ;                  // [B,H,DK,S]
    unsigned short* ctx = vt + NQ;

    dim3 blk(256);
    hipLaunchKernelGGL(cvt_w_kernel, dim3((unsigned)(CVTW_TOTAL / 4 / 256)), blk, 0, stream,
                       w_q, w_k, w_v, w_o, b_q, b_k, b_v, b_o, wqb);
    hipLaunchKernelGGL(qkv_gemm_kernel, dim3(768), blk, 0, stream,
                       q, k, v, wqb, bqb, wkb, bkb, wvb, bvb, qh, kh, vt);
    hipLaunchKernelGGL(attn_kernel, dim3(BATCH * NHEAD, 32), blk, 0, stream,
                       qh, kh, vt, ctx);
    hipLaunchKernelGGL(oproj_gemm_kernel, dim3(1024), blk, 0, stream,
                       ctx, wob, bob, out);
}